// Round 2
// baseline (1516.549 us; speedup 1.0000x reference)
//
#include <hip/hip_runtime.h>
#include <hip/hip_bf16.h>

#define D 256
#define NEG_SLOPE 0.2f

__device__ __forceinline__ float bf2f(unsigned short u) {
    return __uint_as_float(((unsigned int)u) << 16);
}
__device__ __forceinline__ unsigned short f2bf(float f) {
    unsigned int u = __float_as_uint(f);
    unsigned int r = (u + 0x7FFF + ((u >> 16) & 1)) >> 16;  // round-to-nearest-even
    return (unsigned short)r;
}

// ---------------- CSR build ----------------

__global__ void count_kernel(const int* __restrict__ src, int* __restrict__ counts, int E) {
    int t = blockIdx.x * blockDim.x + threadIdx.x;
    if (t < E) atomicAdd(&counts[src[t]], 1);
}

__global__ __launch_bounds__(1024) void scan_kernel(const int* __restrict__ counts,
                                                    int* __restrict__ row_ptr, int n) {
    __shared__ int sums[1024];
    const int tid = threadIdx.x;
    const int chunk = (n + 1023) >> 10;
    const int beg = tid * chunk;
    const int end = min(beg + chunk, n);
    int s = 0;
    for (int i = beg; i < end; ++i) s += counts[i];
    sums[tid] = s;
    __syncthreads();
    for (int off = 1; off < 1024; off <<= 1) {
        int v = (tid >= off) ? sums[tid - off] : 0;
        __syncthreads();
        sums[tid] += v;
        __syncthreads();
    }
    int base = sums[tid] - s;  // exclusive prefix for this thread's chunk
    for (int i = beg; i < end; ++i) { row_ptr[i] = base; base += counts[i]; }
    if (tid == 1023) row_ptr[n] = sums[1023];
}

__global__ void fill_kernel(const int* __restrict__ src, const int* __restrict__ dst,
                            const int* __restrict__ row_ptr, int* __restrict__ fillp,
                            int* __restrict__ col, int E) {
    int t = blockIdx.x * blockDim.x + threadIdx.x;
    if (t < E) {
        int s = src[t];
        int pos = atomicAdd(&fillp[s], 1);
        col[row_ptr[s] + pos] = dst[t];
    }
}

// ---------------- GEMM: C[M,256](bf16) = A[M,256] @ W[256,256](f32) --------
// A either fp32 (Af) or bf16 (Ab). 64x64 tile, 4x4 per thread, fp32 accum.

__global__ __launch_bounds__(256) void gemm256(
    const float* __restrict__ Af, const unsigned short* __restrict__ Ab,
    const float* __restrict__ W, unsigned short* __restrict__ C, int M)
{
    __shared__ float As[16][68];  // [k][m]; stride 68 breaks bank conflicts
    __shared__ float Bs[16][68];  // [k][n]
    const int tid = threadIdx.x;
    const int tx = tid & 15, ty = tid >> 4;
    const int m0 = blockIdx.x * 64, n0 = blockIdx.y * 64;
    const int ar = tid >> 2;          // 0..63 row-in-tile
    const int ak = (tid & 3) * 4;     // k offset 0,4,8,12
    const int bk = tid >> 4;          // 0..15
    const int bn = (tid & 15) * 4;    // 0..60
    const int arow = m0 + ar;
    float acc[4][4] = {};

    for (int k0 = 0; k0 < D; k0 += 16) {
        float av[4];
        if (arow < M) {
            if (Af) {
                const float4 v = *(const float4*)(Af + (size_t)arow * D + k0 + ak);
                av[0] = v.x; av[1] = v.y; av[2] = v.z; av[3] = v.w;
            } else {
                const ushort4 u = *(const ushort4*)(Ab + (size_t)arow * D + k0 + ak);
                av[0] = bf2f(u.x); av[1] = bf2f(u.y); av[2] = bf2f(u.z); av[3] = bf2f(u.w);
            }
        } else {
            av[0] = av[1] = av[2] = av[3] = 0.f;
        }
        As[ak + 0][ar] = av[0];
        As[ak + 1][ar] = av[1];
        As[ak + 2][ar] = av[2];
        As[ak + 3][ar] = av[3];
        {
            const float4 v = *(const float4*)(W + (size_t)(k0 + bk) * D + n0 + bn);
            Bs[bk][bn + 0] = v.x;
            Bs[bk][bn + 1] = v.y;
            Bs[bk][bn + 2] = v.z;
            Bs[bk][bn + 3] = v.w;
        }
        __syncthreads();
        #pragma unroll
        for (int kk = 0; kk < 16; ++kk) {
            const float4 av4 = *(const float4*)&As[kk][ty * 4];
            const float4 bv4 = *(const float4*)&Bs[kk][tx * 4];
            const float aa[4] = {av4.x, av4.y, av4.z, av4.w};
            const float bb[4] = {bv4.x, bv4.y, bv4.z, bv4.w};
            #pragma unroll
            for (int i = 0; i < 4; ++i)
                #pragma unroll
                for (int j = 0; j < 4; ++j)
                    acc[i][j] = fmaf(aa[i], bb[j], acc[i][j]);
        }
        __syncthreads();
    }
    #pragma unroll
    for (int i = 0; i < 4; ++i) {
        const int row = m0 + ty * 4 + i;
        if (row < M) {
            ushort4 o;
            o.x = f2bf(acc[i][0]); o.y = f2bf(acc[i][1]);
            o.z = f2bf(acc[i][2]); o.w = f2bf(acc[i][3]);
            *(ushort4*)(C + (size_t)row * D + n0 + tx * 4) = o;
        }
    }
}

// ---------------- s_src / s_dst: row dot a[:D], a[D:] ----------------

__global__ __launch_bounds__(256) void score_kernel(
    const unsigned short* __restrict__ h2, const float* __restrict__ a,
    float* __restrict__ s_src, float* __restrict__ s_dst, int Nn)
{
    const int lane = threadIdx.x & 63;
    const int w = threadIdx.x >> 6;
    const int row = blockIdx.x * 4 + w;
    if (row >= Nn) return;
    const ushort4 h = *(const ushort4*)(h2 + (size_t)row * D + lane * 4);
    const float4 a1v = *(const float4*)(a + lane * 4);
    const float4 a2v = *(const float4*)(a + D + lane * 4);
    const float hx = bf2f(h.x), hy = bf2f(h.y), hz = bf2f(h.z), hw = bf2f(h.w);
    float p1 = hx * a1v.x + hy * a1v.y + hz * a1v.z + hw * a1v.w;
    float p2 = hx * a2v.x + hy * a2v.y + hz * a2v.z + hw * a2v.w;
    #pragma unroll
    for (int off = 32; off > 0; off >>= 1) {
        p1 += __shfl_down(p1, off);
        p2 += __shfl_down(p2, off);
    }
    if (lane == 0) { s_src[row] = p1; s_dst[row] = p2; }
}

// ---------------- aggregation: block per src node ----------------

__global__ __launch_bounds__(256) void agg_kernel(
    const unsigned short* __restrict__ h2, const float* __restrict__ s_src,
    const float* __restrict__ s_dst, const int* __restrict__ row_ptr,
    const int* __restrict__ col, unsigned short* __restrict__ out_bf16,
    float* __restrict__ out_f32, int Nn)
{
    __shared__ float es[256];
    __shared__ int   cs[256];
    const int i = blockIdx.x;
    const int tid = threadIdx.x;
    const int beg = row_ptr[i], end = row_ptr[i + 1];
    const float ssrc = s_src[i];
    float acc = 0.f, denom = 0.f;
    for (int c0 = beg; c0 < end; c0 += 256) {
        const int cnt = min(256, end - c0);
        if (tid < cnt) {
            const int j = col[c0 + tid];
            cs[tid] = j;
            const float sc = ssrc + s_dst[j];
            const float l = sc >= 0.f ? sc : NEG_SLOPE * sc;
            es[tid] = expf(-l);
        }
        __syncthreads();
        #pragma unroll 4
        for (int k = 0; k < cnt; ++k) {
            const float e = es[k];
            const int j = cs[k];
            acc = fmaf(e, bf2f(h2[(size_t)j * D + tid]), acc);
            denom += e;
        }
        __syncthreads();
    }
    float v = acc / denom;
    v = v > 0.f ? v : expm1f(v);  // elu, alpha=1
    if (out_bf16) out_bf16[(size_t)i * D + tid] = f2bf(v);
    else          out_f32[(size_t)i * D + tid] = v;
}

// ---------------- launch ----------------

static inline size_t align_up(size_t x, size_t a) { return (x + a - 1) & ~(a - 1); }

extern "C" void kernel_launch(void* const* d_in, const int* in_sizes, int n_in,
                              void* d_out, int out_size, void* d_ws, size_t ws_size,
                              hipStream_t stream)
{
    const float* emb = (const float*)d_in[0];
    const float* W1  = (const float*)d_in[1];
    const float* a1  = (const float*)d_in[2];
    const float* W2  = (const float*)d_in[3];
    const float* a2  = (const float*)d_in[4];
    const int* edges = (const int*)d_in[5];
    const int Nn = in_sizes[0] / D;
    const int E  = in_sizes[5] / 2;
    const int* src = edges;
    const int* dst = edges + E;

    size_t off = 0;
    char* base = (char*)d_ws;
    unsigned short* hA = (unsigned short*)(base + off);          // h2 buffer (bf16)
    off = align_up(off + (size_t)Nn * D * sizeof(unsigned short), 256);
    unsigned short* hB = (unsigned short*)(base + off);          // h1 buffer (bf16)
    off = align_up(off + (size_t)Nn * D * sizeof(unsigned short), 256);
    float* s_src = (float*)(base + off); off = align_up(off + (size_t)Nn * sizeof(float), 256);
    float* s_dst = (float*)(base + off); off = align_up(off + (size_t)Nn * sizeof(float), 256);
    int* row_ptr = (int*)(base + off);   off = align_up(off + (size_t)(Nn + 1) * sizeof(int), 256);
    int* counts  = (int*)(base + off);   off = align_up(off + (size_t)Nn * sizeof(int), 256);
    int* fillp   = (int*)(base + off);   off = align_up(off + (size_t)Nn * sizeof(int), 256);
    int* col     = (int*)(base + off);   off = align_up(off + (size_t)E * sizeof(int), 256);

    hipMemsetAsync(counts, 0, (size_t)2 * align_up((size_t)Nn * sizeof(int), 256), stream);
    count_kernel<<<(E + 255) / 256, 256, 0, stream>>>(src, counts, E);
    scan_kernel<<<1, 1024, 0, stream>>>(counts, row_ptr, Nn);
    fill_kernel<<<(E + 255) / 256, 256, 0, stream>>>(src, dst, row_ptr, fillp, col, E);

    dim3 ggrid((Nn + 63) / 64, D / 64);
    // layer 1: h2 = emb @ W1 (bf16 out)
    gemm256<<<ggrid, 256, 0, stream>>>(emb, nullptr, W1, hA, Nn);
    score_kernel<<<(Nn + 3) / 4, 256, 0, stream>>>(hA, a1, s_src, s_dst, Nn);
    agg_kernel<<<Nn, 256, 0, stream>>>(hA, s_src, s_dst, row_ptr, col, hB, nullptr, Nn);
    // layer 2: h2' = h1 @ W2 (reuse hA)
    gemm256<<<ggrid, 256, 0, stream>>>(nullptr, hB, W2, hA, Nn);
    score_kernel<<<(Nn + 3) / 4, 256, 0, stream>>>(hA, a2, s_src, s_dst, Nn);
    agg_kernel<<<Nn, 256, 0, stream>>>(hA, s_src, s_dst, row_ptr, col, nullptr,
                                       (float*)d_out, Nn);
}

// Round 3
// 1231.797 us; speedup vs baseline: 1.2312x; 1.2312x over previous
//
#include <hip/hip_runtime.h>
#include <hip/hip_bf16.h>

#define D 256
#define NEG_SLOPE 0.2f
#define BM 128
#define BN 128
#define BK 64
#define LDK 72   // padded LDS row stride (bf16 elems): 144B = 36 dw == 4 mod 32 banks

using bf16x8 = __attribute__((ext_vector_type(8))) __bf16;
using f32x4  = __attribute__((ext_vector_type(4))) float;

__device__ __forceinline__ float bf2f(unsigned short u) {
    return __uint_as_float(((unsigned int)u) << 16);
}
__device__ __forceinline__ unsigned short f2bf(float f) {
    unsigned int u = __float_as_uint(f);
    unsigned int r = (u + 0x7FFF + ((u >> 16) & 1)) >> 16;  // RNE
    return (unsigned short)r;
}

// ---------------- dtype prep ----------------

__global__ void conv_bf16_kernel(const float* __restrict__ in,
                                 unsigned short* __restrict__ out, int n4) {
    int t = blockIdx.x * blockDim.x + threadIdx.x;
    if (t < n4) {
        const float4 v = *(const float4*)(in + (size_t)t * 4);
        ushort4 o;
        o.x = f2bf(v.x); o.y = f2bf(v.y); o.z = f2bf(v.z); o.w = f2bf(v.w);
        *(ushort4*)(out + (size_t)t * 4) = o;
    }
}

// WT[n][k] = W[k][n], 256x256, bf16 out
__global__ void transW_kernel(const float* __restrict__ W, unsigned short* __restrict__ WT) {
    const int k = blockIdx.x, n = threadIdx.x;
    WT[(size_t)n * D + k] = f2bf(W[(size_t)k * D + n]);
}

// ---------------- CSR build ----------------

__global__ void count_kernel(const int* __restrict__ src, int* __restrict__ counts, int E) {
    int t = blockIdx.x * blockDim.x + threadIdx.x;
    if (t < E) atomicAdd(&counts[src[t]], 1);
}

__global__ __launch_bounds__(1024) void scan_kernel(const int* __restrict__ counts,
                                                    int* __restrict__ row_ptr, int n) {
    __shared__ int sums[1024];
    const int tid = threadIdx.x;
    const int chunk = (n + 1023) >> 10;
    const int beg = tid * chunk;
    const int end = min(beg + chunk, n);
    int s = 0;
    for (int i = beg; i < end; ++i) s += counts[i];
    sums[tid] = s;
    __syncthreads();
    for (int off = 1; off < 1024; off <<= 1) {
        int v = (tid >= off) ? sums[tid - off] : 0;
        __syncthreads();
        sums[tid] += v;
        __syncthreads();
    }
    int base = sums[tid] - s;
    for (int i = beg; i < end; ++i) { row_ptr[i] = base; base += counts[i]; }
    if (tid == 1023) row_ptr[n] = sums[1023];
}

__global__ void fill_kernel(const int* __restrict__ src, const int* __restrict__ dst,
                            const int* __restrict__ row_ptr, int* __restrict__ fillp,
                            int* __restrict__ col, int E) {
    int t = blockIdx.x * blockDim.x + threadIdx.x;
    if (t < E) {
        int s = src[t];
        int pos = atomicAdd(&fillp[s], 1);
        col[row_ptr[s] + pos] = dst[t];
    }
}

// ---------------- MFMA GEMM: C[M,256](bf16) = A[M,256](bf16) @ WT^T -------
// B given as WT[n][k] (bf16) so B-fragments read contiguous k.

__global__ __launch_bounds__(256) void gemm_mfma(
    const unsigned short* __restrict__ A, const unsigned short* __restrict__ BT,
    unsigned short* __restrict__ C, int M)
{
    __shared__ unsigned short smem[2 * BM * LDK];   // 36864 B: A-tile | B-tile
    unsigned short* As_ = smem;
    unsigned short* Bs_ = smem + BM * LDK;
    const int tid = threadIdx.x;
    const int m0 = blockIdx.x * BM;
    const int n0 = blockIdx.y * BN;
    const int lane = tid & 63;
    const int wv = tid >> 6;
    const int wm = (wv & 1) * 64;
    const int wn = (wv >> 1) * 64;
    const int l15 = lane & 15;
    const int quad = lane >> 4;

    f32x4 acc[4][4];
    #pragma unroll
    for (int i = 0; i < 4; ++i)
        #pragma unroll
        for (int j = 0; j < 4; ++j)
            acc[i][j] = (f32x4){0.f, 0.f, 0.f, 0.f};

    for (int k0 = 0; k0 < D; k0 += BK) {
        // stage: 1024 16B-chunks per matrix; thread t takes chunks t, t+256, ...
        #pragma unroll
        for (int c = tid; c < BM * 8; c += 256) {
            const int row = c >> 3, j = c & 7;
            const int gr = m0 + row;
            uint4 av = make_uint4(0, 0, 0, 0);
            if (gr < M) av = *(const uint4*)(A + (size_t)gr * D + k0 + j * 8);
            *(uint4*)(As_ + row * LDK + j * 8) = av;
            const uint4 bv = *(const uint4*)(BT + (size_t)(n0 + row) * D + k0 + j * 8);
            *(uint4*)(Bs_ + row * LDK + j * 8) = bv;
        }
        __syncthreads();
        #pragma unroll
        for (int s = 0; s < 2; ++s) {
            bf16x8 af[4], bfr[4];
            #pragma unroll
            for (int i = 0; i < 4; ++i)
                af[i] = *(const bf16x8*)(As_ + (wm + i * 16 + l15) * LDK + s * 32 + quad * 8);
            #pragma unroll
            for (int j = 0; j < 4; ++j)
                bfr[j] = *(const bf16x8*)(Bs_ + (wn + j * 16 + l15) * LDK + s * 32 + quad * 8);
            #pragma unroll
            for (int i = 0; i < 4; ++i)
                #pragma unroll
                for (int j = 0; j < 4; ++j)
                    acc[i][j] = __builtin_amdgcn_mfma_f32_16x16x32_bf16(
                        af[i], bfr[j], acc[i][j], 0, 0, 0);
        }
        __syncthreads();
    }

    // epilogue: repack via LDS (per-wave 64x72 bf16 region) for coalesced stores
    unsigned short* Cw = smem + wv * (64 * LDK);
    #pragma unroll
    for (int i = 0; i < 4; ++i)
        #pragma unroll
        for (int j = 0; j < 4; ++j)
            #pragma unroll
            for (int r = 0; r < 4; ++r)
                Cw[(i * 16 + quad * 4 + r) * LDK + j * 16 + l15] = f2bf(acc[i][j][r]);
    __syncthreads();
    #pragma unroll
    for (int rr = 0; rr < 64; rr += 2) {
        const int row = rr + (lane >> 5);
        const unsigned int wd = *(const unsigned int*)(Cw + row * LDK + (lane & 31) * 2);
        const int gr = m0 + wm + row;
        if (gr < M)
            *(unsigned int*)(C + (size_t)gr * D + n0 + wn + (lane & 31) * 2) = wd;
    }
}

// ---------------- s_src / s_dst ----------------

__global__ __launch_bounds__(256) void score_kernel(
    const unsigned short* __restrict__ h2, const float* __restrict__ a,
    float* __restrict__ s_src, float* __restrict__ s_dst, int Nn)
{
    const int lane = threadIdx.x & 63;
    const int w = threadIdx.x >> 6;
    const int row = blockIdx.x * 4 + w;
    if (row >= Nn) return;
    const ushort4 h = *(const ushort4*)(h2 + (size_t)row * D + lane * 4);
    const float4 a1v = *(const float4*)(a + lane * 4);
    const float4 a2v = *(const float4*)(a + D + lane * 4);
    const float hx = bf2f(h.x), hy = bf2f(h.y), hz = bf2f(h.z), hw = bf2f(h.w);
    float p1 = hx * a1v.x + hy * a1v.y + hz * a1v.z + hw * a1v.w;
    float p2 = hx * a2v.x + hy * a2v.y + hz * a2v.z + hw * a2v.w;
    #pragma unroll
    for (int off = 32; off > 0; off >>= 1) {
        p1 += __shfl_down(p1, off);
        p2 += __shfl_down(p2, off);
    }
    if (lane == 0) { s_src[row] = p1; s_dst[row] = p2; }
}

// ---------------- aggregation: wave per node ----------------
// lane owns cols [4*lane .. 4*lane+3]; one ushort4 load = full row per edge/wave.

__global__ __launch_bounds__(256) void agg_kernel(
    const unsigned short* __restrict__ h2, const float* __restrict__ s_src,
    const float* __restrict__ s_dst, const int* __restrict__ row_ptr,
    const int* __restrict__ col, unsigned short* __restrict__ out_bf16,
    float* __restrict__ out_f32, int Nn)
{
    const int lane = threadIdx.x & 63;
    const int node = blockIdx.x * 4 + (threadIdx.x >> 6);
    if (node >= Nn) return;
    const int beg = row_ptr[node], end = row_ptr[node + 1];
    const float ssrc = s_src[node];
    float ax = 0.f, ay = 0.f, az = 0.f, aw = 0.f;
    float dpart = 0.f;
    for (int c0 = beg; c0 < end; c0 += 64) {
        const int cnt = min(64, end - c0);
        int j = 0;
        float e = 0.f;
        if (lane < cnt) {
            j = col[c0 + lane];
            const float sc = ssrc + s_dst[j];
            const float l = sc >= 0.f ? sc : NEG_SLOPE * sc;
            e = __expf(-l);
        }
        dpart += e;
        for (int k = 0; k < cnt; ++k) {
            const float ek = __shfl(e, k);   // uniform k -> v_readlane
            const int jk = __shfl(j, k);
            const ushort4 u = *(const ushort4*)(h2 + (size_t)jk * D + lane * 4);
            ax = fmaf(ek, bf2f(u.x), ax);
            ay = fmaf(ek, bf2f(u.y), ay);
            az = fmaf(ek, bf2f(u.z), az);
            aw = fmaf(ek, bf2f(u.w), aw);
        }
    }
    float denom = dpart;
    #pragma unroll
    for (int off = 32; off > 0; off >>= 1) denom += __shfl_xor(denom, off);
    const float inv = 1.f / denom;
    float vx = ax * inv, vy = ay * inv, vz = az * inv, vw = aw * inv;
    vx = vx > 0.f ? vx : expm1f(vx);
    vy = vy > 0.f ? vy : expm1f(vy);
    vz = vz > 0.f ? vz : expm1f(vz);
    vw = vw > 0.f ? vw : expm1f(vw);
    if (out_bf16) {
        ushort4 o;
        o.x = f2bf(vx); o.y = f2bf(vy); o.z = f2bf(vz); o.w = f2bf(vw);
        *(ushort4*)(out_bf16 + (size_t)node * D + lane * 4) = o;
    } else {
        *(float4*)(out_f32 + (size_t)node * D + lane * 4) = make_float4(vx, vy, vz, vw);
    }
}

// ---------------- launch ----------------

static inline size_t align_up(size_t x, size_t a) { return (x + a - 1) & ~(a - 1); }

extern "C" void kernel_launch(void* const* d_in, const int* in_sizes, int n_in,
                              void* d_out, int out_size, void* d_ws, size_t ws_size,
                              hipStream_t stream)
{
    const float* emb = (const float*)d_in[0];
    const float* W1  = (const float*)d_in[1];
    const float* a1  = (const float*)d_in[2];
    const float* W2  = (const float*)d_in[3];
    const float* a2  = (const float*)d_in[4];
    const int* edges = (const int*)d_in[5];
    const int Nn = in_sizes[0] / D;
    const int E  = in_sizes[5] / 2;
    const int* src = edges;
    const int* dst = edges + E;

    size_t off = 0;
    char* base = (char*)d_ws;
    unsigned short* hA = (unsigned short*)(base + off);
    off = align_up(off + (size_t)Nn * D * sizeof(unsigned short), 256);
    unsigned short* hB = (unsigned short*)(base + off);
    off = align_up(off + (size_t)Nn * D * sizeof(unsigned short), 256);
    unsigned short* embb = (unsigned short*)(base + off);
    off = align_up(off + (size_t)Nn * D * sizeof(unsigned short), 256);
    unsigned short* WT1 = (unsigned short*)(base + off);
    off = align_up(off + (size_t)D * D * sizeof(unsigned short), 256);
    unsigned short* WT2 = (unsigned short*)(base + off);
    off = align_up(off + (size_t)D * D * sizeof(unsigned short), 256);
    float* s_src = (float*)(base + off); off = align_up(off + (size_t)Nn * sizeof(float), 256);
    float* s_dst = (float*)(base + off); off = align_up(off + (size_t)Nn * sizeof(float), 256);
    int* row_ptr = (int*)(base + off);   off = align_up(off + (size_t)(Nn + 1) * sizeof(int), 256);
    int* counts  = (int*)(base + off);   off = align_up(off + (size_t)Nn * sizeof(int), 256);
    int* fillp   = (int*)(base + off);   off = align_up(off + (size_t)Nn * sizeof(int), 256);
    int* col     = (int*)(base + off);   off = align_up(off + (size_t)E * sizeof(int), 256);

    // dtype prep
    conv_bf16_kernel<<<(Nn * D / 4 + 255) / 256, 256, 0, stream>>>(emb, embb, Nn * D / 4);
    transW_kernel<<<D, D, 0, stream>>>(W1, WT1);
    transW_kernel<<<D, D, 0, stream>>>(W2, WT2);

    // CSR
    hipMemsetAsync(counts, 0, (size_t)2 * align_up((size_t)Nn * sizeof(int), 256), stream);
    count_kernel<<<(E + 255) / 256, 256, 0, stream>>>(src, counts, E);
    scan_kernel<<<1, 1024, 0, stream>>>(counts, row_ptr, Nn);
    fill_kernel<<<(E + 255) / 256, 256, 0, stream>>>(src, dst, row_ptr, fillp, col, E);

    dim3 ggrid((Nn + BM - 1) / BM, D / BN);
    // layer 1
    gemm_mfma<<<ggrid, 256, 0, stream>>>(embb, WT1, hA, Nn);
    score_kernel<<<(Nn + 3) / 4, 256, 0, stream>>>(hA, a1, s_src, s_dst, Nn);
    agg_kernel<<<(Nn + 3) / 4, 256, 0, stream>>>(hA, s_src, s_dst, row_ptr, col, hB, nullptr, Nn);
    // layer 2
    gemm_mfma<<<ggrid, 256, 0, stream>>>(hB, WT2, hA, Nn);
    score_kernel<<<(Nn + 3) / 4, 256, 0, stream>>>(hA, a2, s_src, s_dst, Nn);
    agg_kernel<<<(Nn + 3) / 4, 256, 0, stream>>>(hA, s_src, s_dst, row_ptr, col, nullptr,
                                                 (float*)d_out, Nn);
}

// Round 4
// 1039.319 us; speedup vs baseline: 1.4592x; 1.1852x over previous
//
#include <hip/hip_runtime.h>
#include <hip/hip_bf16.h>

#define D 256
#define NEG_SLOPE 0.2f
#define BM 128
#define BN 128
#define BK 64
#define LDK 72   // padded LDS row stride (bf16): 144B = 36 dw == 4 mod 32 banks (2-way = free)
#define SCAN_CHUNK 1024

using bf16x8 = __attribute__((ext_vector_type(8))) __bf16;
using f32x4  = __attribute__((ext_vector_type(4))) float;

__device__ __forceinline__ float bf2f(unsigned short u) {
    return __uint_as_float(((unsigned int)u) << 16);
}
__device__ __forceinline__ unsigned short f2bf(float f) {
    unsigned int u = __float_as_uint(f);
    unsigned int r = (u + 0x7FFF + ((u >> 16) & 1)) >> 16;  // RNE
    return (unsigned short)r;
}

// ---------------- dtype prep ----------------

// WT[n][k] = W[k][n], 256x256, bf16 out
__global__ void transW_kernel(const float* __restrict__ W, unsigned short* __restrict__ WT) {
    const int k = blockIdx.x, n = threadIdx.x;
    WT[(size_t)n * D + k] = f2bf(W[(size_t)k * D + n]);
}

// ---------------- CSR build ----------------

__global__ void count_kernel(const int* __restrict__ src, int* __restrict__ counts, int E) {
    int t = blockIdx.x * blockDim.x + threadIdx.x;
    if (t < E) atomicAdd(&counts[src[t]], 1);
}

// pass A: per-chunk sums (coalesced)
__global__ __launch_bounds__(256) void scan_partial_kernel(
    const int* __restrict__ counts, int* __restrict__ partial, int n)
{
    __shared__ int ws[4];
    const int tid = threadIdx.x;
    const int lane = tid & 63, wv = tid >> 6;
    const int idx = blockIdx.x * SCAN_CHUNK + tid * 4;
    int4 v = make_int4(0, 0, 0, 0);
    if (idx + 3 < n) v = *(const int4*)(counts + idx);
    else {
        if (idx + 0 < n) v.x = counts[idx + 0];
        if (idx + 1 < n) v.y = counts[idx + 1];
        if (idx + 2 < n) v.z = counts[idx + 2];
        if (idx + 3 < n) v.w = counts[idx + 3];
    }
    int s = v.x + v.y + v.z + v.w;
    #pragma unroll
    for (int off = 32; off > 0; off >>= 1) s += __shfl_xor(s, off);
    if (lane == 0) ws[wv] = s;
    __syncthreads();
    if (tid == 0) partial[blockIdx.x] = ws[0] + ws[1] + ws[2] + ws[3];
}

// pass B: scan the (<=128) chunk sums; also write row_ptr[n] = total
__global__ __launch_bounds__(128) void scan_chunks_kernel(
    const int* __restrict__ partial, int* __restrict__ chunkoff,
    int* __restrict__ row_ptr, int nchunks, int n)
{
    __shared__ int sm[128];
    const int tid = threadIdx.x;
    const int v = (tid < nchunks) ? partial[tid] : 0;
    sm[tid] = v;
    __syncthreads();
    #pragma unroll
    for (int off = 1; off < 128; off <<= 1) {
        int t = (tid >= off) ? sm[tid - off] : 0;
        __syncthreads();
        sm[tid] += t;
        __syncthreads();
    }
    if (tid < nchunks) chunkoff[tid] = sm[tid] - v;
    if (tid == 127) row_ptr[n] = sm[127];
}

// pass C: in-chunk exclusive scan + chunk offset, coalesced write
__global__ __launch_bounds__(256) void scan_write_kernel(
    const int* __restrict__ counts, const int* __restrict__ chunkoff,
    int* __restrict__ row_ptr, int n)
{
    __shared__ int wsum[4];
    const int tid = threadIdx.x;
    const int lane = tid & 63, wv = tid >> 6;
    const int idx = blockIdx.x * SCAN_CHUNK + tid * 4;
    int4 v = make_int4(0, 0, 0, 0);
    if (idx + 3 < n) v = *(const int4*)(counts + idx);
    else {
        if (idx + 0 < n) v.x = counts[idx + 0];
        if (idx + 1 < n) v.y = counts[idx + 1];
        if (idx + 2 < n) v.z = counts[idx + 2];
        if (idx + 3 < n) v.w = counts[idx + 3];
    }
    const int s = v.x + v.y + v.z + v.w;
    int x = s;
    #pragma unroll
    for (int off = 1; off < 64; off <<= 1) {
        int t = __shfl_up(x, off);
        if (lane >= off) x += t;
    }
    if (lane == 63) wsum[wv] = x;
    __syncthreads();
    int wo = chunkoff[blockIdx.x];
    for (int w = 0; w < 4; ++w) if (w < wv) wo += wsum[w];
    int excl = wo + x - s;
    if (idx + 0 < n) row_ptr[idx + 0] = excl;
    if (idx + 1 < n) row_ptr[idx + 1] = excl + v.x;
    if (idx + 2 < n) row_ptr[idx + 2] = excl + v.x + v.y;
    if (idx + 3 < n) row_ptr[idx + 3] = excl + v.x + v.y + v.z;
}

__global__ void fill_kernel(const int* __restrict__ src, const int* __restrict__ dst,
                            const int* __restrict__ row_ptr, int* __restrict__ fillp,
                            int* __restrict__ col, int E) {
    int t = blockIdx.x * blockDim.x + threadIdx.x;
    if (t < E) {
        int s = src[t];
        int pos = atomicAdd(&fillp[s], 1);
        col[row_ptr[s] + pos] = dst[t];
    }
}

// ---------------- MFMA GEMM: C[M,256](bf16) = A[M,256] @ WT^T -------------
// A from bf16 (Ab) or fp32 (Af, converted during staging). BT[n][k] bf16.

__global__ __launch_bounds__(256) void gemm_mfma(
    const unsigned short* __restrict__ Ab, const float* __restrict__ Af,
    const unsigned short* __restrict__ BT,
    unsigned short* __restrict__ C, int M)
{
    __shared__ unsigned short smem[2 * BM * LDK];   // 36864 B
    unsigned short* As_ = smem;
    unsigned short* Bs_ = smem + BM * LDK;
    const int tid = threadIdx.x;
    const int m0 = blockIdx.x * BM;
    const int n0 = blockIdx.y * BN;
    const int lane = tid & 63;
    const int wv = tid >> 6;
    const int wm = (wv & 1) * 64;
    const int wn = (wv >> 1) * 64;
    const int l15 = lane & 15;
    const int quad = lane >> 4;

    f32x4 acc[4][4];
    #pragma unroll
    for (int i = 0; i < 4; ++i)
        #pragma unroll
        for (int j = 0; j < 4; ++j)
            acc[i][j] = (f32x4){0.f, 0.f, 0.f, 0.f};

    for (int k0 = 0; k0 < D; k0 += BK) {
        #pragma unroll
        for (int c = tid; c < BM * 8; c += 256) {
            const int row = c >> 3, j = c & 7;
            const int gr = m0 + row;
            uint4 av = make_uint4(0, 0, 0, 0);
            if (gr < M) {
                if (Af) {
                    const float* p = Af + (size_t)gr * D + k0 + j * 8;
                    const float4 f0 = *(const float4*)p;
                    const float4 f1 = *(const float4*)(p + 4);
                    av.x = (unsigned int)f2bf(f0.x) | ((unsigned int)f2bf(f0.y) << 16);
                    av.y = (unsigned int)f2bf(f0.z) | ((unsigned int)f2bf(f0.w) << 16);
                    av.z = (unsigned int)f2bf(f1.x) | ((unsigned int)f2bf(f1.y) << 16);
                    av.w = (unsigned int)f2bf(f1.z) | ((unsigned int)f2bf(f1.w) << 16);
                } else {
                    av = *(const uint4*)(Ab + (size_t)gr * D + k0 + j * 8);
                }
            }
            *(uint4*)(As_ + row * LDK + j * 8) = av;
            const uint4 bv = *(const uint4*)(BT + (size_t)(n0 + row) * D + k0 + j * 8);
            *(uint4*)(Bs_ + row * LDK + j * 8) = bv;
        }
        __syncthreads();
        #pragma unroll
        for (int s = 0; s < 2; ++s) {
            bf16x8 af[4], bfr[4];
            #pragma unroll
            for (int i = 0; i < 4; ++i)
                af[i] = *(const bf16x8*)(As_ + (wm + i * 16 + l15) * LDK + s * 32 + quad * 8);
            #pragma unroll
            for (int j = 0; j < 4; ++j)
                bfr[j] = *(const bf16x8*)(Bs_ + (wn + j * 16 + l15) * LDK + s * 32 + quad * 8);
            #pragma unroll
            for (int i = 0; i < 4; ++i)
                #pragma unroll
                for (int j = 0; j < 4; ++j)
                    acc[i][j] = __builtin_amdgcn_mfma_f32_16x16x32_bf16(
                        af[i], bfr[j], acc[i][j], 0, 0, 0);
        }
        __syncthreads();
    }

    // epilogue: repack via LDS for coalesced stores
    unsigned short* Cw = smem + wv * (64 * LDK);
    #pragma unroll
    for (int i = 0; i < 4; ++i)
        #pragma unroll
        for (int j = 0; j < 4; ++j)
            #pragma unroll
            for (int r = 0; r < 4; ++r)
                Cw[(i * 16 + quad * 4 + r) * LDK + j * 16 + l15] = f2bf(acc[i][j][r]);
    __syncthreads();
    #pragma unroll
    for (int rr = 0; rr < 64; rr += 2) {
        const int row = rr + (lane >> 5);
        const unsigned int wd = *(const unsigned int*)(Cw + row * LDK + (lane & 31) * 2);
        const int gr = m0 + wm + row;
        if (gr < M)
            *(unsigned int*)(C + (size_t)gr * D + n0 + wn + (lane & 31) * 2) = wd;
    }
}

// ---------------- s_src / s_dst ----------------

__global__ __launch_bounds__(256) void score_kernel(
    const unsigned short* __restrict__ h2, const float* __restrict__ a,
    float* __restrict__ s_src, float* __restrict__ s_dst, int Nn)
{
    const int lane = threadIdx.x & 63;
    const int w = threadIdx.x >> 6;
    const int row = blockIdx.x * 4 + w;
    if (row >= Nn) return;
    const ushort4 h = *(const ushort4*)(h2 + (size_t)row * D + lane * 4);
    const float4 a1v = *(const float4*)(a + lane * 4);
    const float4 a2v = *(const float4*)(a + D + lane * 4);
    const float hx = bf2f(h.x), hy = bf2f(h.y), hz = bf2f(h.z), hw = bf2f(h.w);
    float p1 = hx * a1v.x + hy * a1v.y + hz * a1v.z + hw * a1v.w;
    float p2 = hx * a2v.x + hy * a2v.y + hz * a2v.z + hw * a2v.w;
    #pragma unroll
    for (int off = 32; off > 0; off >>= 1) {
        p1 += __shfl_down(p1, off);
        p2 += __shfl_down(p2, off);
    }
    if (lane == 0) { s_src[row] = p1; s_dst[row] = p2; }
}

// ---------------- aggregation: wave per node, 4 gathers in flight ---------

__global__ __launch_bounds__(256) void agg_kernel(
    const unsigned short* __restrict__ h2, const float* __restrict__ s_src,
    const float* __restrict__ s_dst, const int* __restrict__ row_ptr,
    const int* __restrict__ col, unsigned short* __restrict__ out_bf16,
    float* __restrict__ out_f32, int Nn)
{
    const int lane = threadIdx.x & 63;
    const int node = blockIdx.x * 4 + (threadIdx.x >> 6);
    if (node >= Nn) return;
    const int beg = row_ptr[node], end = row_ptr[node + 1];
    const float ssrc = s_src[node];
    const unsigned short* hp = h2 + lane * 4;   // lane-fixed column base
    float ax = 0.f, ay = 0.f, az = 0.f, aw = 0.f;
    float dpart = 0.f;
    for (int c0 = beg; c0 < end; c0 += 64) {
        const int cnt = min(64, end - c0);
        int j = 0;
        float e = 0.f;
        if (lane < cnt) {
            j = col[c0 + lane];
            const float sc = ssrc + s_dst[j];
            const float l = sc >= 0.f ? sc : NEG_SLOPE * sc;
            e = __expf(-l);
        }
        dpart += e;
        // 4 edges per iter -> 4 independent gathers in flight (latency hiding).
        // Tail lanes have e=0, j=0: harmless row-0 load, zero contribution.
        for (int k = 0; k < cnt; k += 4) {
            const int   j0 = __shfl(j, k),     j1 = __shfl(j, k + 1);
            const int   j2 = __shfl(j, k + 2), j3 = __shfl(j, k + 3);
            const float e0 = __shfl(e, k),     e1 = __shfl(e, k + 1);
            const float e2 = __shfl(e, k + 2), e3 = __shfl(e, k + 3);
            const ushort4 u0 = *(const ushort4*)(hp + (size_t)j0 * D);
            const ushort4 u1 = *(const ushort4*)(hp + (size_t)j1 * D);
            const ushort4 u2 = *(const ushort4*)(hp + (size_t)j2 * D);
            const ushort4 u3 = *(const ushort4*)(hp + (size_t)j3 * D);
            ax = fmaf(e0, bf2f(u0.x), ax); ay = fmaf(e0, bf2f(u0.y), ay);
            az = fmaf(e0, bf2f(u0.z), az); aw = fmaf(e0, bf2f(u0.w), aw);
            ax = fmaf(e1, bf2f(u1.x), ax); ay = fmaf(e1, bf2f(u1.y), ay);
            az = fmaf(e1, bf2f(u1.z), az); aw = fmaf(e1, bf2f(u1.w), aw);
            ax = fmaf(e2, bf2f(u2.x), ax); ay = fmaf(e2, bf2f(u2.y), ay);
            az = fmaf(e2, bf2f(u2.z), az); aw = fmaf(e2, bf2f(u2.w), aw);
            ax = fmaf(e3, bf2f(u3.x), ax); ay = fmaf(e3, bf2f(u3.y), ay);
            az = fmaf(e3, bf2f(u3.z), az); aw = fmaf(e3, bf2f(u3.w), aw);
        }
    }
    float denom = dpart;
    #pragma unroll
    for (int off = 32; off > 0; off >>= 1) denom += __shfl_xor(denom, off);
    const float inv = 1.f / denom;
    float vx = ax * inv, vy = ay * inv, vz = az * inv, vw = aw * inv;
    vx = vx > 0.f ? vx : expm1f(vx);
    vy = vy > 0.f ? vy : expm1f(vy);
    vz = vz > 0.f ? vz : expm1f(vz);
    vw = vw > 0.f ? vw : expm1f(vw);
    if (out_bf16) {
        ushort4 o;
        o.x = f2bf(vx); o.y = f2bf(vy); o.z = f2bf(vz); o.w = f2bf(vw);
        *(ushort4*)(out_bf16 + (size_t)node * D + lane * 4) = o;
    } else {
        *(float4*)(out_f32 + (size_t)node * D + lane * 4) = make_float4(vx, vy, vz, vw);
    }
}

// ---------------- launch ----------------

static inline size_t align_up(size_t x, size_t a) { return (x + a - 1) & ~(a - 1); }

extern "C" void kernel_launch(void* const* d_in, const int* in_sizes, int n_in,
                              void* d_out, int out_size, void* d_ws, size_t ws_size,
                              hipStream_t stream)
{
    const float* emb = (const float*)d_in[0];
    const float* W1  = (const float*)d_in[1];
    const float* a1  = (const float*)d_in[2];
    const float* W2  = (const float*)d_in[3];
    const float* a2  = (const float*)d_in[4];
    const int* edges = (const int*)d_in[5];
    const int Nn = in_sizes[0] / D;
    const int E  = in_sizes[5] / 2;
    const int* src = edges;
    const int* dst = edges + E;
    const int nchunks = (Nn + SCAN_CHUNK - 1) / SCAN_CHUNK;

    size_t off = 0;
    char* base = (char*)d_ws;
    unsigned short* hA = (unsigned short*)(base + off);
    off = align_up(off + (size_t)Nn * D * sizeof(unsigned short), 256);
    unsigned short* hB = (unsigned short*)(base + off);
    off = align_up(off + (size_t)Nn * D * sizeof(unsigned short), 256);
    unsigned short* WT1 = (unsigned short*)(base + off);
    off = align_up(off + (size_t)D * D * sizeof(unsigned short), 256);
    unsigned short* WT2 = (unsigned short*)(base + off);
    off = align_up(off + (size_t)D * D * sizeof(unsigned short), 256);
    float* s_src = (float*)(base + off); off = align_up(off + (size_t)Nn * sizeof(float), 256);
    float* s_dst = (float*)(base + off); off = align_up(off + (size_t)Nn * sizeof(float), 256);
    int* row_ptr = (int*)(base + off);   off = align_up(off + (size_t)(Nn + 1) * sizeof(int), 256);
    const size_t cstride = align_up((size_t)Nn * sizeof(int), 256);
    int* counts  = (int*)(base + off);   off += cstride;
    int* fillp   = (int*)(base + off);   off += cstride;   // contiguous with counts
    int* partial = (int*)(base + off);   off = align_up(off + (size_t)nchunks * sizeof(int), 256);
    int* chunkoff= (int*)(base + off);   off = align_up(off + (size_t)nchunks * sizeof(int), 256);
    int* col     = (int*)(base + off);   off = align_up(off + (size_t)E * sizeof(int), 256);

    // prep
    transW_kernel<<<D, D, 0, stream>>>(W1, WT1);
    transW_kernel<<<D, D, 0, stream>>>(W2, WT2);

    // CSR (counts+fillp zeroed in one contiguous memset)
    hipMemsetAsync(counts, 0, 2 * cstride, stream);
    count_kernel<<<(E + 255) / 256, 256, 0, stream>>>(src, counts, E);
    scan_partial_kernel<<<nchunks, 256, 0, stream>>>(counts, partial, Nn);
    scan_chunks_kernel<<<1, 128, 0, stream>>>(partial, chunkoff, row_ptr, nchunks, Nn);
    scan_write_kernel<<<nchunks, 256, 0, stream>>>(counts, chunkoff, row_ptr, Nn);
    fill_kernel<<<(E + 255) / 256, 256, 0, stream>>>(src, dst, row_ptr, fillp, col, E);

    dim3 ggrid((Nn + BM - 1) / BM, D / BN);
    // layer 1 (A staged from fp32 emb directly)
    gemm_mfma<<<ggrid, 256, 0, stream>>>(nullptr, emb, WT1, hA, Nn);
    score_kernel<<<(Nn + 3) / 4, 256, 0, stream>>>(hA, a1, s_src, s_dst, Nn);
    agg_kernel<<<(Nn + 3) / 4, 256, 0, stream>>>(hA, s_src, s_dst, row_ptr, col, hB, nullptr, Nn);
    // layer 2
    gemm_mfma<<<ggrid, 256, 0, stream>>>(hB, nullptr, WT2, hA, Nn);
    score_kernel<<<(Nn + 3) / 4, 256, 0, stream>>>(hA, a2, s_src, s_dst, Nn);
    agg_kernel<<<(Nn + 3) / 4, 256, 0, stream>>>(hA, s_src, s_dst, row_ptr, col, nullptr,
                                                 (float*)d_out, Nn);
}